// Round 11
// baseline (110.661 us; speedup 1.0000x reference)
//
#include <hip/hip_runtime.h>
#include <math.h>

// ---------------- persistent device scratch (weights only) ----------------
__device__ __align__(16) float g_w2p[16 * 1152 * 4];  // [blk=ocg4*4+it][oc32][36][4]
__device__ __align__(16) float g_w3p[32 * 1152 * 4];  // [blk=ocg4*8+it][oc32][36][4]
__device__ __align__(16) float g_w4p[8 * 4608 * 4];   // [ocg8][icq][oc16][72][4]
__device__ __align__(16) float g_h1[4 * 30 * 30 * 64];     // [b][r][c][ic]
__device__ __align__(16) float g_h2[4 * 14 * 14 * 4 * 128]; // pool-pair layout
__device__ __align__(16) float g_h3[4 * 6 * 6 * 4 * 128];   // pool-pair layout
__device__ __align__(16) float g_h4[4 * 16 * 128];
// BN stats in d_ws (zeroed by hipMemsetAsync):
//   [0:64)=s1 [64:128)=q1 [128:256)=s2 [256:384)=q2
//   [384:512)=s3 [512:640)=q3 [640:768)=s4 [768:896)=q4

// ---------------- SRN + avgpool2 + bn1 stats (+ w2 repack, inline Gram) ----
// grid 480 = (b, pooled row r, ch2, cqh2); block 256 = 4 waves (rw2 x ph2);
// lane = o; 8 pre-pool positions per lane (halved chain vs R9).
__global__ __launch_bounds__(256) void k_srn(const float* __restrict__ x,
                                             const float* __restrict__ srn_w,
                                             const float* __restrict__ w2,
                                             float* __restrict__ stats) {
    __shared__ __align__(16) float wlds[64 * 244];   // [o][15 rows][16]
    __shared__ float xsm[360];                        // 3c x 6r x 20 cols
    __shared__ float part[2 * 8 * 66];                // [rw][pooled-local][o]
    __shared__ float redS[256], redQ[256];
    int bid = blockIdx.x, t = threadIdx.x;
    int b = bid / 120, rem = bid % 120, r = rem >> 2, sub = rem & 3;
    int ch = sub >> 1, cqh = sub & 1;

    // w2 repack for k_conv2 (single guarded pass: 480*256 >= 73728)
    {
        int j = bid * 256 + t;
        if (j < 73728) {
            int c = j & 3, s4 = j >> 2;
            int sl = s4 % 36, tmp = s4 / 36, oc_l = tmp & 31, blk = tmp >> 5;
            int it = blk & 3, ocg = blk >> 2;
            int kw = sl % 3, icq = (sl / 3) & 3, kh = sl / 12;
            int ic = it * 16 + icq * 4 + c;
            g_w2p[j] = w2[((ocg * 32 + oc_l) * 64 + ic) * 9 + kh * 3 + kw];
        }
    }

    // stage raw srn weights -> [o*244 + (c*5+kh)*16 + kw*3+s]
    float4 wr[15];
#pragma unroll
    for (int k = 0; k < 15; k++) {
        int i4 = k * 256 + t;
        if (i4 < 3600) wr[k] = ((const float4*)srn_w)[i4];
    }
    float xr[2];
#pragma unroll
    for (int k = 0; k < 2; k++) {
        int i = t + k * 256;
        if (i < 360) {
            int c = i / 120, rm = i % 120, rr = rm / 20, col = rm % 20;
            int gc = ch * 30 + cqh * 16 + col; if (gc > 63) gc = 63;
            xr[k] = x[((b * 3 + c) * 64 + (2 * r + rr)) * 64 + gc];
        }
    }
#pragma unroll
    for (int k = 0; k < 15; k++) {
        int i4 = k * 256 + t;
        if (i4 < 3600) {
            float v4[4] = { wr[k].x, wr[k].y, wr[k].z, wr[k].w };
#pragma unroll
            for (int e = 0; e < 4; e++) {
                int i = i4 * 4 + e, o = i / 225, jj = i % 225;
                wlds[o * 244 + (jj / 15) * 16 + (jj % 15)] = v4[e];
            }
        }
    }
#pragma unroll
    for (int k = 0; k < 2; k++) { int i = t + k * 256; if (i < 360) xsm[i] = xr[k]; }
    __syncthreads();

    int w = t >> 6, o = t & 63;
    int rw = w & 1, ph = w >> 1, base = ph * 8;

    float z1[8], z2[8], z3[8], s[8], q[8];
#pragma unroll
    for (int i = 0; i < 8; i++) { z1[i]=0; z2[i]=0; z3[i]=0; s[i]=0; q[i]=0; }

    for (int c = 0; c < 3; c++) {
#pragma unroll
        for (int kh = 0; kh < 5; kh++) {
            float xv[12];
#pragma unroll
            for (int k = 0; k < 12; k++) xv[k] = xsm[(c * 6 + rw + kh) * 20 + base + k];
            float wf[16];
            const float* wp = &wlds[o * 244 + (c * 5 + kh) * 16];
            *(float4*)&wf[0]  = *(const float4*)&wp[0];
            *(float4*)&wf[4]  = *(const float4*)&wp[4];
            *(float4*)&wf[8]  = *(const float4*)&wp[8];
            *(float4*)&wf[12] = *(const float4*)&wp[12];
#pragma unroll
            for (int kw = 0; kw < 5; kw++) {
                float w1 = wf[kw * 3], w2v = wf[kw * 3 + 1], w3v = wf[kw * 3 + 2];
#pragma unroll
                for (int i = 0; i < 8; i++) {
                    float v = xv[kw + i];
                    s[i] += v; q[i] += v * v;
                    z1[i] += w1 * v; z2[i] += w2v * v; z3[i] += w3v * v;
                }
            }
        }
    }

    // per-lane Gram + 4x4 inverse
    float gm[16];
    {
        float c01=0,c02=0,c03=0,c11=0,c12=0,c13=0,c22=0,c23=0,c33=0;
#pragma unroll
        for (int row = 0; row < 15; row++) {
            float wf[16];
            const float* wp = &wlds[o * 244 + row * 16];
            *(float4*)&wf[0]  = *(const float4*)&wp[0];
            *(float4*)&wf[4]  = *(const float4*)&wp[4];
            *(float4*)&wf[8]  = *(const float4*)&wp[8];
            *(float4*)&wf[12] = *(const float4*)&wp[12];
#pragma unroll
            for (int kw = 0; kw < 5; kw++) {
                float w1 = wf[kw*3], w2v = wf[kw*3+1], w3v = wf[kw*3+2];
                c01 += w1; c02 += w2v; c03 += w3v;
                c11 += w1*w1; c12 += w1*w2v; c13 += w1*w3v;
                c22 += w2v*w2v; c23 += w2v*w3v; c33 += w3v*w3v;
            }
        }
        float A[4][8];
        A[0][0]=75.f; A[0][1]=c01; A[0][2]=c02; A[0][3]=c03;
        A[1][0]=c01;  A[1][1]=c11; A[1][2]=c12; A[1][3]=c13;
        A[2][0]=c02;  A[2][1]=c12; A[2][2]=c22; A[2][3]=c23;
        A[3][0]=c03;  A[3][1]=c13; A[3][2]=c23; A[3][3]=c33;
#pragma unroll
        for (int i = 0; i < 4; i++)
#pragma unroll
            for (int j = 0; j < 4; j++) A[i][4 + j] = (i == j) ? 1.f : 0.f;
#pragma unroll
        for (int p = 0; p < 4; p++) {
            float ip = 1.f / A[p][p];
#pragma unroll
            for (int j = 0; j < 8; j++) A[p][j] *= ip;
#pragma unroll
            for (int i = 0; i < 4; i++) if (i != p) {
                float f = A[i][p];
#pragma unroll
                for (int j = 0; j < 8; j++) A[i][j] -= f * A[p][j];
            }
        }
#pragma unroll
        for (int i = 0; i < 4; i++)
#pragma unroll
            for (int j = 0; j < 4; j++) gm[i * 4 + j] = A[i][4 + j];
    }

    const float C1 = 0.36787944117144233f;
    const float INV = 1.5819767068693265f;
#pragma unroll
    for (int pp = 0; pp < 4; pp++) {
        int plb = ph * 4 + pp;          // pooled index local to this block
        int pl = cqh * 8 + plb;         // pooled index within ch window
        if (pl < 15) {
            float aa = 0.f;
#pragma unroll
            for (int e = 0; e < 2; e++) {
                int i = 2 * pp + e;
                float sum = s[i], sq = q[i];
                float gg2 = (sq - sum * sum * (1.f / 75.f)) * (1.f / 74.f);
                float zf[4] = { sum, z1[i], z2[i], z3[i] };
                float qf = 0.f;
#pragma unroll
                for (int f = 0; f < 4; f++) {
                    float acc = 0.f;
#pragma unroll
                    for (int h = 0; h < 4; h++) acc += gm[f * 4 + h] * zf[h];
                    qf += acc * zf[f];
                }
                float err = (sq - qf) / (75.f * gg2);
                aa += (expf(-err) - C1) * INV - 0.5f;
            }
            part[(rw * 8 + plb) * 66 + o] = 0.25f * aa;
        }
    }
    __syncthreads();

    int j2 = t >> 6;
    float ps = 0.f, pq = 0.f;
    for (int plb = j2; plb < 8; plb += 4) {
        int pl = cqh * 8 + plb;
        if (pl < 15) {
            float v = part[plb * 66 + o] + part[(8 + plb) * 66 + o];
            g_h1[((b * 30 + r) * 30 + ch * 15 + pl) * 64 + o] = v;
            ps += v; pq += v * v;
        }
    }
    redS[t] = ps; redQ[t] = pq;
    __syncthreads();
    if (t < 64) {
        atomicAdd(&stats[t],      redS[t] + redS[64 + t] + redS[128 + t] + redS[192 + t]);
        atomicAdd(&stats[64 + t], redQ[t] + redQ[64 + t] + redQ[128 + t] + redQ[192 + t]);
    }
}

// -------- bn1 + conv2 + bn2 stats (+ w3 AND w4 repacks) --------
// grid 896 = (b4, oh28, owh2, ocg4); block 256 = oc_l(32) x grp(8);
// grp<6: 2 ow, grp>=6: 1 ow. 2 staging rounds x 2 tiles.
__global__ __launch_bounds__(256) void k_conv2(const float* __restrict__ w3,
                                               const float* __restrict__ w4,
                                               const float* __restrict__ g1,
                                               const float* __restrict__ b1,
                                               float* __restrict__ stats) {
    __shared__ __align__(16) float ws[2 * 32 * 148];
    __shared__ __align__(16) float xs[3 * 16 * 64];
    __shared__ float redS[256], redQ[256];
    int blk = blockIdx.x, t = threadIdx.x;
    int b = blk / 224, rem = blk % 224, oh = rem >> 3, sub = rem & 7;
    int owh = sub >> 2, ocg = sub & 3;
    int oc_l = t & 31, grp = t >> 5;
    int now = (grp < 6) ? 2 : 1;
    int lowb = (grp < 6) ? grp * 2 : 12 + (grp - 6);

    // w3 repack for k_conv3 (single guarded pass)
    {
        int j = blk * 256 + t;
        if (j < 147456) {
            int c = j & 3, s4 = j >> 2;
            int sl = s4 % 36, tmp = s4 / 36, oc2 = tmp & 31, bk = tmp >> 5;
            int it = bk & 7, og = bk >> 3;
            int kw = sl % 3, icq = (sl / 3) & 3, kh = sl / 12;
            int ic = it * 16 + icq * 4 + c;
            g_w3p[j] = w3[((og * 32 + oc2) * 128 + ic) * 9 + kh * 3 + kw];
        }
    }
    // w4 repack for k_conv4 (single guarded pass; conv3 stays preamble-free)
    {
        int j = blk * 256 + t;
        if (j < 147456) {
            int c = j & 3, s4 = j >> 2;
            int sl = s4 % 72, tmp = s4 / 72, oc2 = tmp & 15, blkq = tmp >> 4;
            int icq = blkq & 3, og = blkq >> 2;
            int kw = sl % 3, icb2 = (sl / 3) & 7, kh = sl / 24;
            int ic = icq * 32 + icb2 * 4 + c;
            g_w4p[j] = w4[((og * 16 + oc2) * 128 + ic) * 9 + kh * 3 + kw];
        }
    }

    const float4* wsrc = (const float4*)g_w2p + (ocg * 4) * 1152;
    {
        int icb = (t & 15) * 4;
        float4 S = *(const float4*)&stats[icb], Q = *(const float4*)&stats[64 + icb];
        float4 G4 = *(const float4*)&g1[icb], B4 = *(const float4*)&b1[icb];
        float scv[4], shv[4];
        float mm[4] = { S.x, S.y, S.z, S.w }, qq[4] = { Q.x, Q.y, Q.z, Q.w };
        float gg[4] = { G4.x, G4.y, G4.z, G4.w }, bb[4] = { B4.x, B4.y, B4.z, B4.w };
#pragma unroll
        for (int c = 0; c < 4; c++) {
            float m = mm[c] * (1.f / 3600.f);
            float v = qq[c] * (1.f / 3600.f) - m * m;
            scv[c] = gg[c] * rsqrtf(v + 1e-5f);
            shv[c] = bb[c] - m * scv[c];
        }
        int px = t >> 4, ic4 = t & 15;
        float4 xr[3];
#pragma unroll
        for (int k = 0; k < 3; k++)
            xr[k] = ((const float4*)g_h1)[((b * 30 + oh + k) * 30 + owh * 14 + px) * 16 + ic4];
        float4 wreg[9];
#pragma unroll
        for (int k = 0; k < 9; k++) wreg[k] = wsrc[k * 256 + t];
#pragma unroll
        for (int k = 0; k < 3; k++) {
            float4 v;
            v.x = xr[k].x * scv[0] + shv[0]; v.y = xr[k].y * scv[1] + shv[1];
            v.z = xr[k].z * scv[2] + shv[2]; v.w = xr[k].w * scv[3] + shv[3];
            *(float4*)&xs[((k * 16 + px) * 16 + ic4) * 4] = v;
        }
#pragma unroll
        for (int k = 0; k < 9; k++) {
            int idx = k * 256 + t;
            int tile = idx / 1152, r2 = idx % 1152;
            *(float4*)&ws[tile * 4736 + (r2 / 36) * 148 + (r2 % 36) * 4] = wreg[k];
        }
    }
    __syncthreads();

    float acc[2] = {0, 0};
    for (int rr = 0; rr < 2; ++rr) {
        float4 wreg[9];
        if (rr == 0) {
#pragma unroll
            for (int k = 0; k < 9; k++) wreg[k] = wsrc[2 * 1152 + k * 256 + t];
        }
        for (int half = 0; half < 2; ++half) {
            int it = rr * 2 + half;
            const float* wB = &ws[half * 4736 + oc_l * 148];
#pragma unroll 1
            for (int icq = 0; icq < 4; icq++) {
                int xoff = it * 16 + icq * 4;
#pragma unroll
                for (int kh = 0; kh < 3; kh++) {
                    const float* wb = &wB[(kh * 4 + icq) * 12];
                    float4 w0 = *(const float4*)&wb[0];
                    float4 w1 = *(const float4*)&wb[4];
                    float4 w2v = *(const float4*)&wb[8];
                    const float* xrow = &xs[(kh * 16 + lowb) * 64 + xoff];
                    float4 x0 = *(const float4*)&xrow[0];
                    float4 x1 = *(const float4*)&xrow[64];
#pragma unroll
                    for (int i = 0; i < 2; i++) {
                        if (i < now) {
                            float4 x2 = *(const float4*)&xrow[(i + 2) * 64];
                            acc[i] += w0.x * x0.x + w0.y * x0.y + w0.z * x0.z + w0.w * x0.w
                                    + w1.x * x1.x + w1.y * x1.y + w1.z * x1.z + w1.w * x1.w
                                    + w2v.x * x2.x + w2v.y * x2.y + w2v.z * x2.z + w2v.w * x2.w;
                            x0 = x1; x1 = x2;
                        }
                    }
                }
            }
        }
        if (rr == 0) {
            __syncthreads();
#pragma unroll
            for (int k = 0; k < 9; k++) {
                int idx = k * 256 + t;
                int tile = idx / 1152, r2 = idx % 1152;
                *(float4*)&ws[tile * 4736 + (r2 / 36) * 148 + (r2 % 36) * 4] = wreg[k];
            }
            __syncthreads();
        }
    }
    int oc = ocg * 32 + oc_l;
    float ps = 0.f, pq = 0.f;
#pragma unroll
    for (int i = 0; i < 2; i++) {
        if (i < now) {
            int ow = owh * 14 + lowb + i;
            g_h2[(((b * 14 + (oh >> 1)) * 14 + (ow >> 1)) * 4 + (oh & 1) * 2 + (ow & 1)) * 128 + oc] = acc[i];
            ps += acc[i]; pq += acc[i] * acc[i];
        }
    }
    redS[t] = ps; redQ[t] = pq;
    __syncthreads();
    if (t < 32) {
        float aS = 0.f, aQ = 0.f;
#pragma unroll
        for (int k = 0; k < 8; k++) { aS += redS[t + 32 * k]; aQ += redQ[t + 32 * k]; }
        atomicAdd(&stats[128 + ocg * 32 + t], aS);
        atomicAdd(&stats[256 + ocg * 32 + t], aQ);
    }
}

// -------- bn2+relu+avgpool2 + conv3 + bn3 stats (preamble-free) --------
// grid 192 = (b4, oh12, ocg4); block 256 = oc_l(32) x grp(8);
// grp<4: 2 ow, grp>=4: 1 ow. 4 staging rounds x 2 tiles.
__global__ __launch_bounds__(256) void k_conv3(const float* __restrict__ g2,
                                               const float* __restrict__ b2,
                                               float* __restrict__ stats) {
    __shared__ __align__(16) float ws[2 * 32 * 148];
    __shared__ __align__(16) float xs[3 * 14 * 128];
    __shared__ float redS[256], redQ[256];
    int blk = blockIdx.x, t = threadIdx.x;
    int b = blk / 48, rem = blk % 48, oh = rem >> 2, ocg = rem & 3;
    int oc_l = t & 31, grp = t >> 5;
    int now = (grp < 4) ? 2 : 1;
    int lowb = (grp < 4) ? grp * 2 : 8 + (grp - 4);

    const float4* wsrc = (const float4*)g_w3p + (ocg * 8) * 1152;
    {
        int icb = (t & 31) * 4;
        float4 S = *(const float4*)&stats[128 + icb], Q = *(const float4*)&stats[256 + icb];
        float4 G4 = *(const float4*)&g2[icb], B4 = *(const float4*)&b2[icb];
        float scv[4], shv[4];
        float mm[4] = { S.x, S.y, S.z, S.w }, qq[4] = { Q.x, Q.y, Q.z, Q.w };
        float gg[4] = { G4.x, G4.y, G4.z, G4.w }, bb[4] = { B4.x, B4.y, B4.z, B4.w };
#pragma unroll
        for (int c = 0; c < 4; c++) {
            float m = mm[c] * (1.f / 3136.f);
            float v = qq[c] * (1.f / 3136.f) - m * m;
            scv[c] = gg[c] * rsqrtf(v + 1e-5f);
            shv[c] = bb[c] - m * scv[c];
        }
        float4 wreg[9];
#pragma unroll
        for (int k = 0; k < 9; k++) wreg[k] = wsrc[k * 256 + t];
        float4 pa[6], pb[6], pc[6], pd[6];
#pragma unroll
        for (int k = 0; k < 6; k++) {
            int i4 = t + k * 256;
            if (i4 < 1344) {
                int px = (i4 >> 5) % 14, rr2 = i4 / 448;
                const float4* p0 = (const float4*)&g_h2[(((b * 14 + oh + rr2) * 14 + px) * 4) * 128 + (i4 & 31) * 4];
                pa[k] = p0[0]; pb[k] = p0[32]; pc[k] = p0[64]; pd[k] = p0[96];
            }
        }
#pragma unroll
        for (int k = 0; k < 9; k++) {
            int idx = k * 256 + t;
            int tile = idx / 1152, r2 = idx % 1152;
            *(float4*)&ws[tile * 4736 + (r2 / 36) * 148 + (r2 % 36) * 4] = wreg[k];
        }
#pragma unroll
        for (int k = 0; k < 6; k++) {
            int i4 = t + k * 256;
            if (i4 < 1344) {
                float4 o4;
                o4.x = 0.25f * (fmaxf(pa[k].x * scv[0] + shv[0], 0.f) + fmaxf(pb[k].x * scv[0] + shv[0], 0.f)
                              + fmaxf(pc[k].x * scv[0] + shv[0], 0.f) + fmaxf(pd[k].x * scv[0] + shv[0], 0.f));
                o4.y = 0.25f * (fmaxf(pa[k].y * scv[1] + shv[1], 0.f) + fmaxf(pb[k].y * scv[1] + shv[1], 0.f)
                              + fmaxf(pc[k].y * scv[1] + shv[1], 0.f) + fmaxf(pd[k].y * scv[1] + shv[1], 0.f));
                o4.z = 0.25f * (fmaxf(pa[k].z * scv[2] + shv[2], 0.f) + fmaxf(pb[k].z * scv[2] + shv[2], 0.f)
                              + fmaxf(pc[k].z * scv[2] + shv[2], 0.f) + fmaxf(pd[k].z * scv[2] + shv[2], 0.f));
                o4.w = 0.25f * (fmaxf(pa[k].w * scv[3] + shv[3], 0.f) + fmaxf(pb[k].w * scv[3] + shv[3], 0.f)
                              + fmaxf(pc[k].w * scv[3] + shv[3], 0.f) + fmaxf(pd[k].w * scv[3] + shv[3], 0.f));
                *(float4*)&xs[i4 * 4] = o4;
            }
        }
    }
    __syncthreads();

    float acc[2] = {0, 0};
    for (int rr = 0; rr < 4; ++rr) {
        float4 wreg[9];
        if (rr < 3) {
#pragma unroll
            for (int k = 0; k < 9; k++) wreg[k] = wsrc[(2 * rr + 2) * 1152 + k * 256 + t];
        }
        for (int half = 0; half < 2; ++half) {
            int it = rr * 2 + half;
            const float* wB = &ws[half * 4736 + oc_l * 148];
#pragma unroll 1
            for (int icq = 0; icq < 4; icq++) {
                int xoff = it * 16 + icq * 4;
#pragma unroll
                for (int kh = 0; kh < 3; kh++) {
                    const float* wb = &wB[(kh * 4 + icq) * 12];
                    float4 w0 = *(const float4*)&wb[0];
                    float4 w1 = *(const float4*)&wb[4];
                    float4 w2v = *(const float4*)&wb[8];
                    const float* xrow = &xs[(kh * 14 + lowb) * 128 + xoff];
                    float4 x0 = *(const float4*)&xrow[0];
                    float4 x1 = *(const float4*)&xrow[128];
#pragma unroll
                    for (int i = 0; i < 2; i++) {
                        if (i < now) {
                            float4 x2 = *(const float4*)&xrow[(i + 2) * 128];
                            acc[i] += w0.x * x0.x + w0.y * x0.y + w0.z * x0.z + w0.w * x0.w
                                    + w1.x * x1.x + w1.y * x1.y + w1.z * x1.z + w1.w * x1.w
                                    + w2v.x * x2.x + w2v.y * x2.y + w2v.z * x2.z + w2v.w * x2.w;
                            x0 = x1; x1 = x2;
                        }
                    }
                }
            }
        }
        if (rr < 3) {
            __syncthreads();
#pragma unroll
            for (int k = 0; k < 9; k++) {
                int idx = k * 256 + t;
                int tile = idx / 1152, r2 = idx % 1152;
                *(float4*)&ws[tile * 4736 + (r2 / 36) * 148 + (r2 % 36) * 4] = wreg[k];
            }
            __syncthreads();
        }
    }
    int oc = ocg * 32 + oc_l;
    float ps = 0.f, pq = 0.f;
#pragma unroll
    for (int i = 0; i < 2; i++) {
        if (i < now) {
            int ow = lowb + i;
            g_h3[(((b * 6 + (oh >> 1)) * 6 + (ow >> 1)) * 4 + (oh & 1) * 2 + (ow & 1)) * 128 + oc] = acc[i];
            ps += acc[i]; pq += acc[i] * acc[i];
        }
    }
    redS[t] = ps; redQ[t] = pq;
    __syncthreads();
    if (t < 32) {
        float aS = 0.f, aQ = 0.f;
#pragma unroll
        for (int k = 0; k < 8; k++) { aS += redS[t + 32 * k]; aQ += redQ[t + 32 * k]; }
        atomicAdd(&stats[384 + ocg * 32 + t], aS);
        atomicAdd(&stats[512 + ocg * 32 + t], aQ);
    }
}

// -------- bn3+relu+maxpool2 + conv4 + bn4 stats --------
// grid 128 = (b, oh4, ocg8); block 256 = oc_l(16) x ow(4) x icq(4=wave)
__global__ __launch_bounds__(256) void k_conv4(const float* __restrict__ g3,
                                               const float* __restrict__ b3,
                                               float* __restrict__ stats) {
    __shared__ __align__(16) float ws[64 * 292];
    __shared__ __align__(16) float xs[3 * 6 * 128];
    __shared__ float red[256];
    int blk = blockIdx.x, t = threadIdx.x;
    int b = blk / 32, rem = blk % 32, oh = rem / 8, ocg = rem % 8;
    int oc_l = t & 15, ow = (t >> 4) & 3, icq = t >> 6;

    {
        int icb = (t & 31) * 4;
        float4 S = *(const float4*)&stats[384 + icb], Q = *(const float4*)&stats[512 + icb];
        float4 G4 = *(const float4*)&g3[icb], B4 = *(const float4*)&b3[icb];
        float scv[4], shv[4];
        float mm[4] = { S.x, S.y, S.z, S.w }, qq[4] = { Q.x, Q.y, Q.z, Q.w };
        float gg[4] = { G4.x, G4.y, G4.z, G4.w }, bb[4] = { B4.x, B4.y, B4.z, B4.w };
#pragma unroll
        for (int c = 0; c < 4; c++) {
            float m = mm[c] * (1.f / 576.f);
            float v = qq[c] * (1.f / 576.f) - m * m;
            scv[c] = gg[c] * rsqrtf(v + 1e-5f);
            shv[c] = bb[c] - m * scv[c];
        }
        const float4* wsrc = (const float4*)g_w4p + ocg * 4608;
        float4 wreg[18];
#pragma unroll
        for (int k = 0; k < 18; k++) wreg[k] = wsrc[k * 256 + t];
        float4 pa[3], pb[3], pc[3], pd[3];
#pragma unroll
        for (int k = 0; k < 3; k++) {
            int i4 = t + k * 256;
            if (i4 < 576) {
                int px = (i4 >> 5) % 6, rr = i4 / 192;
                const float4* p0 = (const float4*)&g_h3[(((b * 6 + oh + rr) * 6 + px) * 4) * 128 + (i4 & 31) * 4];
                pa[k] = p0[0]; pb[k] = p0[32]; pc[k] = p0[64]; pd[k] = p0[96];
            }
        }
#pragma unroll
        for (int k = 0; k < 18; k++) {
            int idx = k * 256 + t;
            *(float4*)&ws[(idx / 72) * 292 + (idx % 72) * 4] = wreg[k];
        }
#pragma unroll
        for (int k = 0; k < 3; k++) {
            int i4 = t + k * 256;
            if (i4 < 576) {
                float4 o4;
                o4.x = fmaxf(fmaxf(fmaxf(pa[k].x * scv[0] + shv[0], pb[k].x * scv[0] + shv[0]),
                                   fmaxf(pc[k].x * scv[0] + shv[0], pd[k].x * scv[0] + shv[0])), 0.f);
                o4.y = fmaxf(fmaxf(fmaxf(pa[k].y * scv[1] + shv[1], pb[k].y * scv[1] + shv[1]),
                                   fmaxf(pc[k].y * scv[1] + shv[1], pd[k].y * scv[1] + shv[1])), 0.f);
                o4.z = fmaxf(fmaxf(fmaxf(pa[k].z * scv[2] + shv[2], pb[k].z * scv[2] + shv[2]),
                                   fmaxf(pc[k].z * scv[2] + shv[2], pd[k].z * scv[2] + shv[2])), 0.f);
                o4.w = fmaxf(fmaxf(fmaxf(pa[k].w * scv[3] + shv[3], pb[k].w * scv[3] + shv[3]),
                                   fmaxf(pc[k].w * scv[3] + shv[3], pd[k].w * scv[3] + shv[3])), 0.f);
                *(float4*)&xs[i4 * 4] = o4;
            }
        }
    }
    __syncthreads();

    float acc = 0.f;
    const float* wbase = &ws[(icq * 16 + oc_l) * 292];
#pragma unroll 1
    for (int icbq = 0; icbq < 8; icbq++) {
#pragma unroll
        for (int kh = 0; kh < 3; kh++) {
            const float* wb = &wbase[(kh * 8 + icbq) * 12];
            float4 w0 = *(const float4*)&wb[0];
            float4 w1 = *(const float4*)&wb[4];
            float4 w2v = *(const float4*)&wb[8];
            float4 x0 = *(const float4*)&xs[(kh * 6 + ow) * 128 + icq * 32 + icbq * 4];
            float4 x1 = *(const float4*)&xs[(kh * 6 + ow + 1) * 128 + icq * 32 + icbq * 4];
            float4 x2 = *(const float4*)&xs[(kh * 6 + ow + 2) * 128 + icq * 32 + icbq * 4];
            acc += w0.x * x0.x + w0.y * x0.y + w0.z * x0.z + w0.w * x0.w
                 + w1.x * x1.x + w1.y * x1.y + w1.z * x1.z + w1.w * x1.w
                 + w2v.x * x2.x + w2v.y * x2.y + w2v.z * x2.z + w2v.w * x2.w;
        }
    }
    red[t] = acc;
    __syncthreads();
    if (t < 64) {
        float v = red[t] + red[t + 64] + red[t + 128] + red[t + 192];
        int oc = ocg * 16 + (t & 15);
        g_h4[((b * 4 + oh) * 4 + (t >> 4)) * 128 + oc] = v;
        float ps = v + __shfl_xor(v, 16);  ps += __shfl_xor(ps, 32);
        float pv = v * v;
        float pq = pv + __shfl_xor(pv, 16); pq += __shfl_xor(pq, 32);
        if (t < 16) {
            atomicAdd(&stats[640 + ocg * 16 + t], ps);
            atomicAdd(&stats[768 + ocg * 16 + t], pq);
        }
    }
}

// ------- bn4+relu+maxpool4 + FC -------
__global__ __launch_bounds__(256) void k_final(const float* __restrict__ g4,
                                               const float* __restrict__ b4,
                                               const float* __restrict__ fcw,
                                               const float* __restrict__ fcb,
                                               const float* __restrict__ stats,
                                               float* __restrict__ out) {
    __shared__ float sc[128], sh[128];
    __shared__ float pooled[4][128];
    int t = threadIdx.x;
    if (t < 128) {
        float m = stats[640 + t] * (1.f / 64.f);
        float v = stats[768 + t] * (1.f / 64.f) - m * m;
        float rs = rsqrtf(v + 1e-5f);
        sc[t] = g4[t] * rs; sh[t] = b4[t] - m * sc[t];
    }
    __syncthreads();
    for (int item = t; item < 512; item += 256) {
        int bb = item >> 7, oc = item & 127;
        float s = sc[oc], h = sh[oc];
        float mx = 0.f;
#pragma unroll
        for (int k = 0; k < 16; k++) mx = fmaxf(mx, g_h4[(bb * 16 + k) * 128 + oc] * s + h);
        pooled[bb][oc] = mx;
    }
    __syncthreads();
    if (t < 20) {
        int bb = t / 5, cls = t % 5;
        float acc = fcb[cls];
        const float* w = &fcw[cls * 128];
        for (int oc = 0; oc < 128; oc++) acc += pooled[bb][oc] * w[oc];
        out[bb * 5 + cls] = acc;
    }
}

extern "C" void kernel_launch(void* const* d_in, const int* in_sizes, int n_in,
                              void* d_out, int out_size, void* d_ws, size_t ws_size,
                              hipStream_t stream) {
    (void)in_sizes; (void)n_in; (void)out_size; (void)ws_size;
    const float* x     = (const float*)d_in[0];
    const float* srn_w = (const float*)d_in[1];
    const float* w2    = (const float*)d_in[2];
    const float* w3    = (const float*)d_in[4];
    const float* w4    = (const float*)d_in[6];
    const float* g1 = (const float*)d_in[8];  const float* b1 = (const float*)d_in[9];
    const float* g2 = (const float*)d_in[10]; const float* b2 = (const float*)d_in[11];
    const float* g3 = (const float*)d_in[12]; const float* b3 = (const float*)d_in[13];
    const float* g4 = (const float*)d_in[14]; const float* b4 = (const float*)d_in[15];
    const float* fcw = (const float*)d_in[16]; const float* fcb = (const float*)d_in[17];
    float* out = (float*)d_out;
    float* stats = (float*)d_ws;   // 896 floats of BN-stat accumulators

    hipMemsetAsync(d_ws, 0, 4096, stream);
    k_srn  <<<dim3(480), dim3(256), 0, stream>>>(x, srn_w, w2, stats);
    k_conv2<<<dim3(896), dim3(256), 0, stream>>>(w3, w4, g1, b1, stats);
    k_conv3<<<dim3(192), dim3(256), 0, stream>>>(g2, b2, stats);
    k_conv4<<<dim3(128), dim3(256), 0, stream>>>(g3, b3, stats);
    k_final<<<dim3(1),   dim3(256), 0, stream>>>(g4, b4, fcw, fcb, stats, out);
}

// Round 12
// 101.713 us; speedup vs baseline: 1.0880x; 1.0880x over previous
//
#include <hip/hip_runtime.h>
#include <math.h>

// ---------------- persistent device scratch (weights only) ----------------
__device__ __align__(16) float g_w2p[16 * 1152 * 4];  // [blk=ocg4*4+it][oc32][36][4]
__device__ __align__(16) float g_w3p[32 * 1152 * 4];  // [blk=ocg4*8+it][oc32][36][4]
__device__ __align__(16) float g_w4p[8 * 4608 * 4];   // [ocg8][icq][oc16][72][4]
__device__ __align__(16) float g_h1[4 * 30 * 30 * 64];     // [b][r][c][ic]
__device__ __align__(16) float g_h2[4 * 14 * 14 * 4 * 128]; // pool-pair layout
__device__ __align__(16) float g_h3[4 * 6 * 6 * 4 * 128];   // pool-pair layout
__device__ __align__(16) float g_h4[4 * 16 * 128];
// BN stats in d_ws (zeroed by hipMemsetAsync):
//   [0:64)=s1 [64:128)=q1 [128:256)=s2 [256:384)=q2
//   [384:512)=s3 [512:640)=q3 [640:768)=s4 [768:896)=q4

// ---------------- SRN + avgpool2 + bn1 stats (+ w2 repack, inline Gram) ----
// grid 240 = (b, pooled row r, col-half); block 256 = 4 waves; lane = o.
// (R9-proven version)
__global__ __launch_bounds__(256) void k_srn(const float* __restrict__ x,
                                             const float* __restrict__ srn_w,
                                             const float* __restrict__ w2,
                                             float* __restrict__ stats) {
    __shared__ __align__(16) float wlds[64 * 244];   // [o][15 rows][16]
    __shared__ float xsm[648];
    __shared__ float part[2 * 15 * 66];
    __shared__ float redS[256], redQ[256];
    int bid = blockIdx.x, t = threadIdx.x;
    int b = bid / 60, rem = bid % 60, r = rem >> 1, ch = rem & 1;

    // w2 repack for k_conv2 (32-oc tile layout)
    for (int j = bid * 256 + t; j < 73728; j += 240 * 256) {
        int c = j & 3, s4 = j >> 2;
        int sl = s4 % 36, tmp = s4 / 36, oc_l = tmp & 31, blk = tmp >> 5;
        int it = blk & 3, ocg = blk >> 2;
        int kw = sl % 3, icq = (sl / 3) & 3, kh = sl / 12;
        int ic = it * 16 + icq * 4 + c;
        g_w2p[j] = w2[((ocg * 32 + oc_l) * 64 + ic) * 9 + kh * 3 + kw];
    }

    // stage raw srn weights -> [o*244 + (c*5+kh)*16 + kw*3+s]
    float4 wr[15];
#pragma unroll
    for (int k = 0; k < 15; k++) {
        int i4 = k * 256 + t;
        if (i4 < 3600) wr[k] = ((const float4*)srn_w)[i4];
    }
    float xr[3];
#pragma unroll
    for (int k = 0; k < 3; k++) {
        int i = t + k * 256;
        if (i < 648) {
            int c = i / 216, rm = i % 216, rr = rm / 36, col = rm % 36;
            int gc = ch * 30 + col; if (gc > 63) gc = 63;
            xr[k] = x[((b * 3 + c) * 64 + (2 * r + rr)) * 64 + gc];
        }
    }
#pragma unroll
    for (int k = 0; k < 15; k++) {
        int i4 = k * 256 + t;
        if (i4 < 3600) {
            float v4[4] = { wr[k].x, wr[k].y, wr[k].z, wr[k].w };
#pragma unroll
            for (int e = 0; e < 4; e++) {
                int i = i4 * 4 + e, o = i / 225, jj = i % 225;
                wlds[o * 244 + (jj / 15) * 16 + (jj % 15)] = v4[e];
            }
        }
    }
#pragma unroll
    for (int k = 0; k < 3; k++) { int i = t + k * 256; if (i < 648) xsm[i] = xr[k]; }
    __syncthreads();

    int w = t >> 6, o = t & 63;
    int rw = w & 1, cq = w >> 1, base = cq * 16;

    float z1[16], z2[16], z3[16], s[16], q[16];
#pragma unroll
    for (int i = 0; i < 16; i++) { z1[i]=0; z2[i]=0; z3[i]=0; s[i]=0; q[i]=0; }

    for (int c = 0; c < 3; c++) {
#pragma unroll
        for (int kh = 0; kh < 5; kh++) {
            float xv[20];
#pragma unroll
            for (int k = 0; k < 20; k++) xv[k] = xsm[(c * 6 + rw + kh) * 36 + base + k];
            float wf[16];
            const float* wp = &wlds[o * 244 + (c * 5 + kh) * 16];
            *(float4*)&wf[0]  = *(const float4*)&wp[0];
            *(float4*)&wf[4]  = *(const float4*)&wp[4];
            *(float4*)&wf[8]  = *(const float4*)&wp[8];
            *(float4*)&wf[12] = *(const float4*)&wp[12];
#pragma unroll
            for (int kw = 0; kw < 5; kw++) {
                float w1 = wf[kw * 3], w2v = wf[kw * 3 + 1], w3v = wf[kw * 3 + 2];
#pragma unroll
                for (int i = 0; i < 16; i++) {
                    float v = xv[kw + i];
                    s[i] += v; q[i] += v * v;
                    z1[i] += w1 * v; z2[i] += w2v * v; z3[i] += w3v * v;
                }
            }
        }
    }

    // per-lane Gram + 4x4 inverse
    float gm[16];
    {
        float c01=0,c02=0,c03=0,c11=0,c12=0,c13=0,c22=0,c23=0,c33=0;
#pragma unroll
        for (int row = 0; row < 15; row++) {
            float wf[16];
            const float* wp = &wlds[o * 244 + row * 16];
            *(float4*)&wf[0]  = *(const float4*)&wp[0];
            *(float4*)&wf[4]  = *(const float4*)&wp[4];
            *(float4*)&wf[8]  = *(const float4*)&wp[8];
            *(float4*)&wf[12] = *(const float4*)&wp[12];
#pragma unroll
            for (int kw = 0; kw < 5; kw++) {
                float w1 = wf[kw*3], w2v = wf[kw*3+1], w3v = wf[kw*3+2];
                c01 += w1; c02 += w2v; c03 += w3v;
                c11 += w1*w1; c12 += w1*w2v; c13 += w1*w3v;
                c22 += w2v*w2v; c23 += w2v*w3v; c33 += w3v*w3v;
            }
        }
        float A[4][8];
        A[0][0]=75.f; A[0][1]=c01; A[0][2]=c02; A[0][3]=c03;
        A[1][0]=c01;  A[1][1]=c11; A[1][2]=c12; A[1][3]=c13;
        A[2][0]=c02;  A[2][1]=c12; A[2][2]=c22; A[2][3]=c23;
        A[3][0]=c03;  A[3][1]=c13; A[3][2]=c23; A[3][3]=c33;
#pragma unroll
        for (int i = 0; i < 4; i++)
#pragma unroll
            for (int j = 0; j < 4; j++) A[i][4 + j] = (i == j) ? 1.f : 0.f;
#pragma unroll
        for (int p = 0; p < 4; p++) {
            float ip = 1.f / A[p][p];
#pragma unroll
            for (int j = 0; j < 8; j++) A[p][j] *= ip;
#pragma unroll
            for (int i = 0; i < 4; i++) if (i != p) {
                float f = A[i][p];
#pragma unroll
                for (int j = 0; j < 8; j++) A[i][j] -= f * A[p][j];
            }
        }
#pragma unroll
        for (int i = 0; i < 4; i++)
#pragma unroll
            for (int j = 0; j < 4; j++) gm[i * 4 + j] = A[i][4 + j];
    }

    const float C1 = 0.36787944117144233f;
    const float INV = 1.5819767068693265f;
#pragma unroll
    for (int pp = 0; pp < 8; pp++) {
        int pl = cq * 8 + pp;
        if (pl < 15) {
            float aa = 0.f;
#pragma unroll
            for (int e = 0; e < 2; e++) {
                int i = 2 * pp + e;
                float sum = s[i], sq = q[i];
                float gg2 = (sq - sum * sum * (1.f / 75.f)) * (1.f / 74.f);
                float zf[4] = { sum, z1[i], z2[i], z3[i] };
                float qf = 0.f;
#pragma unroll
                for (int f = 0; f < 4; f++) {
                    float acc = 0.f;
#pragma unroll
                    for (int h = 0; h < 4; h++) acc += gm[f * 4 + h] * zf[h];
                    qf += acc * zf[f];
                }
                float err = (sq - qf) / (75.f * gg2);
                aa += (expf(-err) - C1) * INV - 0.5f;
            }
            part[(rw * 15 + pl) * 66 + o] = 0.25f * aa;
        }
    }
    __syncthreads();

    int j2 = t >> 6;
    float ps = 0.f, pq = 0.f;
    for (int pl = j2; pl < 15; pl += 4) {
        float v = part[pl * 66 + o] + part[(15 + pl) * 66 + o];
        g_h1[((b * 30 + r) * 30 + ch * 15 + pl) * 64 + o] = v;
        ps += v; pq += v * v;
    }
    redS[t] = ps; redQ[t] = pq;
    __syncthreads();
    if (t < 64) {
        atomicAdd(&stats[t],      redS[t] + redS[64 + t] + redS[128 + t] + redS[192 + t]);
        atomicAdd(&stats[64 + t], redQ[t] + redQ[64 + t] + redQ[128 + t] + redQ[192 + t]);
    }
}

// -------- bn1 + conv2 + bn2 stats (+ w3 AND w4 repacks) --------
// grid 896 = (b4, oh28, owh2, ocg4); block 256 = oc_l(32) x grp(8);
// grp<6: 2 ow, grp>=6: 1 ow. 2 staging rounds x 2 tiles.
__global__ __launch_bounds__(256) void k_conv2(const float* __restrict__ w3,
                                               const float* __restrict__ w4,
                                               const float* __restrict__ g1,
                                               const float* __restrict__ b1,
                                               float* __restrict__ stats) {
    __shared__ __align__(16) float ws[2 * 32 * 148];
    __shared__ __align__(16) float xs[3 * 16 * 64];
    __shared__ float redS[256], redQ[256];
    int blk = blockIdx.x, t = threadIdx.x;
    int b = blk / 224, rem = blk % 224, oh = rem >> 3, sub = rem & 7;
    int owh = sub >> 2, ocg = sub & 3;
    int oc_l = t & 31, grp = t >> 5;
    int now = (grp < 6) ? 2 : 1;
    int lowb = (grp < 6) ? grp * 2 : 12 + (grp - 6);

    // w3 repack for k_conv3 (single guarded pass)
    {
        int j = blk * 256 + t;
        if (j < 147456) {
            int c = j & 3, s4 = j >> 2;
            int sl = s4 % 36, tmp = s4 / 36, oc2 = tmp & 31, bk = tmp >> 5;
            int it = bk & 7, og = bk >> 3;
            int kw = sl % 3, icq = (sl / 3) & 3, kh = sl / 12;
            int ic = it * 16 + icq * 4 + c;
            g_w3p[j] = w3[((og * 32 + oc2) * 128 + ic) * 9 + kh * 3 + kw];
        }
    }
    // w4 repack for k_conv4 (single guarded pass; conv3 stays preamble-free)
    {
        int j = blk * 256 + t;
        if (j < 147456) {
            int c = j & 3, s4 = j >> 2;
            int sl = s4 % 72, tmp = s4 / 72, oc2 = tmp & 15, blkq = tmp >> 4;
            int icq = blkq & 3, og = blkq >> 2;
            int kw = sl % 3, icb2 = (sl / 3) & 7, kh = sl / 24;
            int ic = icq * 32 + icb2 * 4 + c;
            g_w4p[j] = w4[((og * 16 + oc2) * 128 + ic) * 9 + kh * 3 + kw];
        }
    }

    const float4* wsrc = (const float4*)g_w2p + (ocg * 4) * 1152;
    {
        int icb = (t & 15) * 4;
        float4 S = *(const float4*)&stats[icb], Q = *(const float4*)&stats[64 + icb];
        float4 G4 = *(const float4*)&g1[icb], B4 = *(const float4*)&b1[icb];
        float scv[4], shv[4];
        float mm[4] = { S.x, S.y, S.z, S.w }, qq[4] = { Q.x, Q.y, Q.z, Q.w };
        float gg[4] = { G4.x, G4.y, G4.z, G4.w }, bb[4] = { B4.x, B4.y, B4.z, B4.w };
#pragma unroll
        for (int c = 0; c < 4; c++) {
            float m = mm[c] * (1.f / 3600.f);
            float v = qq[c] * (1.f / 3600.f) - m * m;
            scv[c] = gg[c] * rsqrtf(v + 1e-5f);
            shv[c] = bb[c] - m * scv[c];
        }
        int px = t >> 4, ic4 = t & 15;
        float4 xr[3];
#pragma unroll
        for (int k = 0; k < 3; k++)
            xr[k] = ((const float4*)g_h1)[((b * 30 + oh + k) * 30 + owh * 14 + px) * 16 + ic4];
        float4 wreg[9];
#pragma unroll
        for (int k = 0; k < 9; k++) wreg[k] = wsrc[k * 256 + t];
#pragma unroll
        for (int k = 0; k < 3; k++) {
            float4 v;
            v.x = xr[k].x * scv[0] + shv[0]; v.y = xr[k].y * scv[1] + shv[1];
            v.z = xr[k].z * scv[2] + shv[2]; v.w = xr[k].w * scv[3] + shv[3];
            *(float4*)&xs[((k * 16 + px) * 16 + ic4) * 4] = v;
        }
#pragma unroll
        for (int k = 0; k < 9; k++) {
            int idx = k * 256 + t;
            int tile = idx / 1152, r2 = idx % 1152;
            *(float4*)&ws[tile * 4736 + (r2 / 36) * 148 + (r2 % 36) * 4] = wreg[k];
        }
    }
    __syncthreads();

    float acc[2] = {0, 0};
    for (int rr = 0; rr < 2; ++rr) {
        float4 wreg[9];
        if (rr == 0) {
#pragma unroll
            for (int k = 0; k < 9; k++) wreg[k] = wsrc[2 * 1152 + k * 256 + t];
        }
        for (int half = 0; half < 2; ++half) {
            int it = rr * 2 + half;
            const float* wB = &ws[half * 4736 + oc_l * 148];
#pragma unroll 1
            for (int icq = 0; icq < 4; icq++) {
                int xoff = it * 16 + icq * 4;
#pragma unroll
                for (int kh = 0; kh < 3; kh++) {
                    const float* wb = &wB[(kh * 4 + icq) * 12];
                    float4 w0 = *(const float4*)&wb[0];
                    float4 w1 = *(const float4*)&wb[4];
                    float4 w2v = *(const float4*)&wb[8];
                    const float* xrow = &xs[(kh * 16 + lowb) * 64 + xoff];
                    float4 x0 = *(const float4*)&xrow[0];
                    float4 x1 = *(const float4*)&xrow[64];
#pragma unroll
                    for (int i = 0; i < 2; i++) {
                        if (i < now) {
                            float4 x2 = *(const float4*)&xrow[(i + 2) * 64];
                            acc[i] += w0.x * x0.x + w0.y * x0.y + w0.z * x0.z + w0.w * x0.w
                                    + w1.x * x1.x + w1.y * x1.y + w1.z * x1.z + w1.w * x1.w
                                    + w2v.x * x2.x + w2v.y * x2.y + w2v.z * x2.z + w2v.w * x2.w;
                            x0 = x1; x1 = x2;
                        }
                    }
                }
            }
        }
        if (rr == 0) {
            __syncthreads();
#pragma unroll
            for (int k = 0; k < 9; k++) {
                int idx = k * 256 + t;
                int tile = idx / 1152, r2 = idx % 1152;
                *(float4*)&ws[tile * 4736 + (r2 / 36) * 148 + (r2 % 36) * 4] = wreg[k];
            }
            __syncthreads();
        }
    }
    int oc = ocg * 32 + oc_l;
    float ps = 0.f, pq = 0.f;
#pragma unroll
    for (int i = 0; i < 2; i++) {
        if (i < now) {
            int ow = owh * 14 + lowb + i;
            g_h2[(((b * 14 + (oh >> 1)) * 14 + (ow >> 1)) * 4 + (oh & 1) * 2 + (ow & 1)) * 128 + oc] = acc[i];
            ps += acc[i]; pq += acc[i] * acc[i];
        }
    }
    redS[t] = ps; redQ[t] = pq;
    __syncthreads();
    if (t < 32) {
        float aS = 0.f, aQ = 0.f;
#pragma unroll
        for (int k = 0; k < 8; k++) { aS += redS[t + 32 * k]; aQ += redQ[t + 32 * k]; }
        atomicAdd(&stats[128 + ocg * 32 + t], aS);
        atomicAdd(&stats[256 + ocg * 32 + t], aQ);
    }
}

// -------- bn2+relu+avgpool2 + conv3 + bn3 stats (preamble-free) --------
// grid 192 = (b4, oh12, ocg4); block 256 = oc_l(32) x grp(8);
// grp<4: 2 ow, grp>=4: 1 ow. 4 staging rounds x 2 tiles.
__global__ __launch_bounds__(256) void k_conv3(const float* __restrict__ g2,
                                               const float* __restrict__ b2,
                                               float* __restrict__ stats) {
    __shared__ __align__(16) float ws[2 * 32 * 148];
    __shared__ __align__(16) float xs[3 * 14 * 128];
    __shared__ float redS[256], redQ[256];
    int blk = blockIdx.x, t = threadIdx.x;
    int b = blk / 48, rem = blk % 48, oh = rem >> 2, ocg = rem & 3;
    int oc_l = t & 31, grp = t >> 5;
    int now = (grp < 4) ? 2 : 1;
    int lowb = (grp < 4) ? grp * 2 : 8 + (grp - 4);

    const float4* wsrc = (const float4*)g_w3p + (ocg * 8) * 1152;
    {
        int icb = (t & 31) * 4;
        float4 S = *(const float4*)&stats[128 + icb], Q = *(const float4*)&stats[256 + icb];
        float4 G4 = *(const float4*)&g2[icb], B4 = *(const float4*)&b2[icb];
        float scv[4], shv[4];
        float mm[4] = { S.x, S.y, S.z, S.w }, qq[4] = { Q.x, Q.y, Q.z, Q.w };
        float gg[4] = { G4.x, G4.y, G4.z, G4.w }, bb[4] = { B4.x, B4.y, B4.z, B4.w };
#pragma unroll
        for (int c = 0; c < 4; c++) {
            float m = mm[c] * (1.f / 3136.f);
            float v = qq[c] * (1.f / 3136.f) - m * m;
            scv[c] = gg[c] * rsqrtf(v + 1e-5f);
            shv[c] = bb[c] - m * scv[c];
        }
        float4 wreg[9];
#pragma unroll
        for (int k = 0; k < 9; k++) wreg[k] = wsrc[k * 256 + t];
        float4 pa[6], pb[6], pc[6], pd[6];
#pragma unroll
        for (int k = 0; k < 6; k++) {
            int i4 = t + k * 256;
            if (i4 < 1344) {
                int px = (i4 >> 5) % 14, rr2 = i4 / 448;
                const float4* p0 = (const float4*)&g_h2[(((b * 14 + oh + rr2) * 14 + px) * 4) * 128 + (i4 & 31) * 4];
                pa[k] = p0[0]; pb[k] = p0[32]; pc[k] = p0[64]; pd[k] = p0[96];
            }
        }
#pragma unroll
        for (int k = 0; k < 9; k++) {
            int idx = k * 256 + t;
            int tile = idx / 1152, r2 = idx % 1152;
            *(float4*)&ws[tile * 4736 + (r2 / 36) * 148 + (r2 % 36) * 4] = wreg[k];
        }
#pragma unroll
        for (int k = 0; k < 6; k++) {
            int i4 = t + k * 256;
            if (i4 < 1344) {
                float4 o4;
                o4.x = 0.25f * (fmaxf(pa[k].x * scv[0] + shv[0], 0.f) + fmaxf(pb[k].x * scv[0] + shv[0], 0.f)
                              + fmaxf(pc[k].x * scv[0] + shv[0], 0.f) + fmaxf(pd[k].x * scv[0] + shv[0], 0.f));
                o4.y = 0.25f * (fmaxf(pa[k].y * scv[1] + shv[1], 0.f) + fmaxf(pb[k].y * scv[1] + shv[1], 0.f)
                              + fmaxf(pc[k].y * scv[1] + shv[1], 0.f) + fmaxf(pd[k].y * scv[1] + shv[1], 0.f));
                o4.z = 0.25f * (fmaxf(pa[k].z * scv[2] + shv[2], 0.f) + fmaxf(pb[k].z * scv[2] + shv[2], 0.f)
                              + fmaxf(pc[k].z * scv[2] + shv[2], 0.f) + fmaxf(pd[k].z * scv[2] + shv[2], 0.f));
                o4.w = 0.25f * (fmaxf(pa[k].w * scv[3] + shv[3], 0.f) + fmaxf(pb[k].w * scv[3] + shv[3], 0.f)
                              + fmaxf(pc[k].w * scv[3] + shv[3], 0.f) + fmaxf(pd[k].w * scv[3] + shv[3], 0.f));
                *(float4*)&xs[i4 * 4] = o4;
            }
        }
    }
    __syncthreads();

    float acc[2] = {0, 0};
    for (int rr = 0; rr < 4; ++rr) {
        float4 wreg[9];
        if (rr < 3) {
#pragma unroll
            for (int k = 0; k < 9; k++) wreg[k] = wsrc[(2 * rr + 2) * 1152 + k * 256 + t];
        }
        for (int half = 0; half < 2; ++half) {
            int it = rr * 2 + half;
            const float* wB = &ws[half * 4736 + oc_l * 148];
#pragma unroll 1
            for (int icq = 0; icq < 4; icq++) {
                int xoff = it * 16 + icq * 4;
#pragma unroll
                for (int kh = 0; kh < 3; kh++) {
                    const float* wb = &wB[(kh * 4 + icq) * 12];
                    float4 w0 = *(const float4*)&wb[0];
                    float4 w1 = *(const float4*)&wb[4];
                    float4 w2v = *(const float4*)&wb[8];
                    const float* xrow = &xs[(kh * 14 + lowb) * 128 + xoff];
                    float4 x0 = *(const float4*)&xrow[0];
                    float4 x1 = *(const float4*)&xrow[128];
#pragma unroll
                    for (int i = 0; i < 2; i++) {
                        if (i < now) {
                            float4 x2 = *(const float4*)&xrow[(i + 2) * 128];
                            acc[i] += w0.x * x0.x + w0.y * x0.y + w0.z * x0.z + w0.w * x0.w
                                    + w1.x * x1.x + w1.y * x1.y + w1.z * x1.z + w1.w * x1.w
                                    + w2v.x * x2.x + w2v.y * x2.y + w2v.z * x2.z + w2v.w * x2.w;
                            x0 = x1; x1 = x2;
                        }
                    }
                }
            }
        }
        if (rr < 3) {
            __syncthreads();
#pragma unroll
            for (int k = 0; k < 9; k++) {
                int idx = k * 256 + t;
                int tile = idx / 1152, r2 = idx % 1152;
                *(float4*)&ws[tile * 4736 + (r2 / 36) * 148 + (r2 % 36) * 4] = wreg[k];
            }
            __syncthreads();
        }
    }
    int oc = ocg * 32 + oc_l;
    float ps = 0.f, pq = 0.f;
#pragma unroll
    for (int i = 0; i < 2; i++) {
        if (i < now) {
            int ow = lowb + i;
            g_h3[(((b * 6 + (oh >> 1)) * 6 + (ow >> 1)) * 4 + (oh & 1) * 2 + (ow & 1)) * 128 + oc] = acc[i];
            ps += acc[i]; pq += acc[i] * acc[i];
        }
    }
    redS[t] = ps; redQ[t] = pq;
    __syncthreads();
    if (t < 32) {
        float aS = 0.f, aQ = 0.f;
#pragma unroll
        for (int k = 0; k < 8; k++) { aS += redS[t + 32 * k]; aQ += redQ[t + 32 * k]; }
        atomicAdd(&stats[384 + ocg * 32 + t], aS);
        atomicAdd(&stats[512 + ocg * 32 + t], aQ);
    }
}

// -------- bn3+relu+maxpool2 + conv4 + bn4 stats --------
// grid 128 = (b, oh4, ocg8); block 256 = oc_l(16) x ow(4) x icq(4=wave)
__global__ __launch_bounds__(256) void k_conv4(const float* __restrict__ g3,
                                               const float* __restrict__ b3,
                                               float* __restrict__ stats) {
    __shared__ __align__(16) float ws[64 * 292];
    __shared__ __align__(16) float xs[3 * 6 * 128];
    __shared__ float red[256];
    int blk = blockIdx.x, t = threadIdx.x;
    int b = blk / 32, rem = blk % 32, oh = rem / 8, ocg = rem % 8;
    int oc_l = t & 15, ow = (t >> 4) & 3, icq = t >> 6;

    {
        int icb = (t & 31) * 4;
        float4 S = *(const float4*)&stats[384 + icb], Q = *(const float4*)&stats[512 + icb];
        float4 G4 = *(const float4*)&g3[icb], B4 = *(const float4*)&b3[icb];
        float scv[4], shv[4];
        float mm[4] = { S.x, S.y, S.z, S.w }, qq[4] = { Q.x, Q.y, Q.z, Q.w };
        float gg[4] = { G4.x, G4.y, G4.z, G4.w }, bb[4] = { B4.x, B4.y, B4.z, B4.w };
#pragma unroll
        for (int c = 0; c < 4; c++) {
            float m = mm[c] * (1.f / 576.f);
            float v = qq[c] * (1.f / 576.f) - m * m;
            scv[c] = gg[c] * rsqrtf(v + 1e-5f);
            shv[c] = bb[c] - m * scv[c];
        }
        const float4* wsrc = (const float4*)g_w4p + ocg * 4608;
        float4 wreg[18];
#pragma unroll
        for (int k = 0; k < 18; k++) wreg[k] = wsrc[k * 256 + t];
        float4 pa[3], pb[3], pc[3], pd[3];
#pragma unroll
        for (int k = 0; k < 3; k++) {
            int i4 = t + k * 256;
            if (i4 < 576) {
                int px = (i4 >> 5) % 6, rr = i4 / 192;
                const float4* p0 = (const float4*)&g_h3[(((b * 6 + oh + rr) * 6 + px) * 4) * 128 + (i4 & 31) * 4];
                pa[k] = p0[0]; pb[k] = p0[32]; pc[k] = p0[64]; pd[k] = p0[96];
            }
        }
#pragma unroll
        for (int k = 0; k < 18; k++) {
            int idx = k * 256 + t;
            *(float4*)&ws[(idx / 72) * 292 + (idx % 72) * 4] = wreg[k];
        }
#pragma unroll
        for (int k = 0; k < 3; k++) {
            int i4 = t + k * 256;
            if (i4 < 576) {
                float4 o4;
                o4.x = fmaxf(fmaxf(fmaxf(pa[k].x * scv[0] + shv[0], pb[k].x * scv[0] + shv[0]),
                                   fmaxf(pc[k].x * scv[0] + shv[0], pd[k].x * scv[0] + shv[0])), 0.f);
                o4.y = fmaxf(fmaxf(fmaxf(pa[k].y * scv[1] + shv[1], pb[k].y * scv[1] + shv[1]),
                                   fmaxf(pc[k].y * scv[1] + shv[1], pd[k].y * scv[1] + shv[1])), 0.f);
                o4.z = fmaxf(fmaxf(fmaxf(pa[k].z * scv[2] + shv[2], pb[k].z * scv[2] + shv[2]),
                                   fmaxf(pc[k].z * scv[2] + shv[2], pd[k].z * scv[2] + shv[2])), 0.f);
                o4.w = fmaxf(fmaxf(fmaxf(pa[k].w * scv[3] + shv[3], pb[k].w * scv[3] + shv[3]),
                                   fmaxf(pc[k].w * scv[3] + shv[3], pd[k].w * scv[3] + shv[3])), 0.f);
                *(float4*)&xs[i4 * 4] = o4;
            }
        }
    }
    __syncthreads();

    float acc = 0.f;
    const float* wbase = &ws[(icq * 16 + oc_l) * 292];
#pragma unroll 1
    for (int icbq = 0; icbq < 8; icbq++) {
#pragma unroll
        for (int kh = 0; kh < 3; kh++) {
            const float* wb = &wbase[(kh * 8 + icbq) * 12];
            float4 w0 = *(const float4*)&wb[0];
            float4 w1 = *(const float4*)&wb[4];
            float4 w2v = *(const float4*)&wb[8];
            float4 x0 = *(const float4*)&xs[(kh * 6 + ow) * 128 + icq * 32 + icbq * 4];
            float4 x1 = *(const float4*)&xs[(kh * 6 + ow + 1) * 128 + icq * 32 + icbq * 4];
            float4 x2 = *(const float4*)&xs[(kh * 6 + ow + 2) * 128 + icq * 32 + icbq * 4];
            acc += w0.x * x0.x + w0.y * x0.y + w0.z * x0.z + w0.w * x0.w
                 + w1.x * x1.x + w1.y * x1.y + w1.z * x1.z + w1.w * x1.w
                 + w2v.x * x2.x + w2v.y * x2.y + w2v.z * x2.z + w2v.w * x2.w;
        }
    }
    red[t] = acc;
    __syncthreads();
    if (t < 64) {
        float v = red[t] + red[t + 64] + red[t + 128] + red[t + 192];
        int oc = ocg * 16 + (t & 15);
        g_h4[((b * 4 + oh) * 4 + (t >> 4)) * 128 + oc] = v;
        float ps = v + __shfl_xor(v, 16);  ps += __shfl_xor(ps, 32);
        float pv = v * v;
        float pq = pv + __shfl_xor(pv, 16); pq += __shfl_xor(pq, 32);
        if (t < 16) {
            atomicAdd(&stats[640 + ocg * 16 + t], ps);
            atomicAdd(&stats[768 + ocg * 16 + t], pq);
        }
    }
}

// ------- bn4+relu+maxpool4 + FC -------
__global__ __launch_bounds__(256) void k_final(const float* __restrict__ g4,
                                               const float* __restrict__ b4,
                                               const float* __restrict__ fcw,
                                               const float* __restrict__ fcb,
                                               const float* __restrict__ stats,
                                               float* __restrict__ out) {
    __shared__ float sc[128], sh[128];
    __shared__ float pooled[4][128];
    int t = threadIdx.x;
    if (t < 128) {
        float m = stats[640 + t] * (1.f / 64.f);
        float v = stats[768 + t] * (1.f / 64.f) - m * m;
        float rs = rsqrtf(v + 1e-5f);
        sc[t] = g4[t] * rs; sh[t] = b4[t] - m * sc[t];
    }
    __syncthreads();
    for (int item = t; item < 512; item += 256) {
        int bb = item >> 7, oc = item & 127;
        float s = sc[oc], h = sh[oc];
        float mx = 0.f;
#pragma unroll
        for (int k = 0; k < 16; k++) mx = fmaxf(mx, g_h4[(bb * 16 + k) * 128 + oc] * s + h);
        pooled[bb][oc] = mx;
    }
    __syncthreads();
    if (t < 20) {
        int bb = t / 5, cls = t % 5;
        float acc = fcb[cls];
        const float* w = &fcw[cls * 128];
        for (int oc = 0; oc < 128; oc++) acc += pooled[bb][oc] * w[oc];
        out[bb * 5 + cls] = acc;
    }
}

extern "C" void kernel_launch(void* const* d_in, const int* in_sizes, int n_in,
                              void* d_out, int out_size, void* d_ws, size_t ws_size,
                              hipStream_t stream) {
    (void)in_sizes; (void)n_in; (void)out_size; (void)ws_size;
    const float* x     = (const float*)d_in[0];
    const float* srn_w = (const float*)d_in[1];
    const float* w2    = (const float*)d_in[2];
    const float* w3    = (const float*)d_in[4];
    const float* w4    = (const float*)d_in[6];
    const float* g1 = (const float*)d_in[8];  const float* b1 = (const float*)d_in[9];
    const float* g2 = (const float*)d_in[10]; const float* b2 = (const float*)d_in[11];
    const float* g3 = (const float*)d_in[12]; const float* b3 = (const float*)d_in[13];
    const float* g4 = (const float*)d_in[14]; const float* b4 = (const float*)d_in[15];
    const float* fcw = (const float*)d_in[16]; const float* fcb = (const float*)d_in[17];
    float* out = (float*)d_out;
    float* stats = (float*)d_ws;   // 896 floats of BN-stat accumulators

    hipMemsetAsync(d_ws, 0, 4096, stream);
    k_srn  <<<dim3(240), dim3(256), 0, stream>>>(x, srn_w, w2, stats);
    k_conv2<<<dim3(896), dim3(256), 0, stream>>>(w3, w4, g1, b1, stats);
    k_conv3<<<dim3(192), dim3(256), 0, stream>>>(g2, b2, stats);
    k_conv4<<<dim3(128), dim3(256), 0, stream>>>(g3, b3, stats);
    k_final<<<dim3(1),   dim3(256), 0, stream>>>(g4, b4, fcw, fcb, stats, out);
}

// Round 13
// 99.188 us; speedup vs baseline: 1.1157x; 1.0255x over previous
//
#include <hip/hip_runtime.h>
#include <math.h>

// ---------------- persistent device scratch (weights only) ----------------
__device__ __align__(16) float g_w2p[16 * 1152 * 4];  // [blk=ocg4*4+it][oc32][36][4]
__device__ __align__(16) float g_w3p[32 * 1152 * 4];  // [blk=ocg4*8+it][oc32][36][4]
__device__ __align__(16) float g_w4p[8 * 4608 * 4];   // [ocg8][icq][oc16][72][4]
__device__ __align__(16) float g_h1[4 * 30 * 30 * 64];     // [b][r][c][ic]
__device__ __align__(16) float g_h2[4 * 14 * 14 * 4 * 128]; // pool-pair layout
__device__ __align__(16) float g_h3[4 * 6 * 6 * 4 * 128];   // pool-pair layout
__device__ __align__(16) float g_h4[4 * 16 * 128];
// BN stats in d_ws (zeroed by hipMemsetAsync):
//   [0:64)=s1 [64:128)=q1 [128:256)=s2 [256:384)=q2
//   [384:512)=s3 [512:640)=q3 [640:768)=s4 [768:896)=q4

// ---------------- SRN + avgpool2 + bn1 stats (+ w2 repack, inline Gram) ----
// grid 240 = (b, pooled row r, col-half); block 512 = 8 waves (rw2 x cq4);
// lane = o, 8 pre-pool positions/lane. Gram folded into the main loop.
// LDS: xsm[648] | wlds[64*244]; part/redS/redQ alias wlds after the main loop.
__global__ __launch_bounds__(512) void k_srn(const float* __restrict__ x,
                                             const float* __restrict__ srn_w,
                                             const float* __restrict__ w2,
                                             float* __restrict__ stats) {
    __shared__ __align__(16) float smem[16264];   // 65056 B
    float* xsm  = smem;            // [648]
    float* wlds = smem + 648;      // [64*244]
    float* part = smem + 648;      // aliases wlds (dead after main loop)
    float* redS = smem + 2628;     // 648+1980
    float* redQ = smem + 3140;
    int bid = blockIdx.x, t = threadIdx.x;
    int b = bid / 60, rem = bid % 60, r = rem >> 1, ch = rem & 1;

    // w2 repack for k_conv2 (single guarded pass: 240*512 >= 73728)
    {
        int j = bid * 512 + t;
        if (j < 73728) {
            int c = j & 3, s4 = j >> 2;
            int sl = s4 % 36, tmp = s4 / 36, oc_l = tmp & 31, blk = tmp >> 5;
            int it = blk & 3, ocg = blk >> 2;
            int kw = sl % 3, icq = (sl / 3) & 3, kh = sl / 12;
            int ic = it * 16 + icq * 4 + c;
            g_w2p[j] = w2[((ocg * 32 + oc_l) * 64 + ic) * 9 + kh * 3 + kw];
        }
    }

    // stage raw srn weights -> wlds[o*244 + (c*5+kh)*16 + kw*3+s]
    float4 wr[8];
#pragma unroll
    for (int k = 0; k < 8; k++) {
        int i4 = k * 512 + t;
        if (i4 < 3600) wr[k] = ((const float4*)srn_w)[i4];
    }
    float xr[2];
#pragma unroll
    for (int k = 0; k < 2; k++) {
        int i = t + k * 512;
        if (i < 648) {
            int c = i / 216, rm = i % 216, rr = rm / 36, col = rm % 36;
            int gc = ch * 30 + col; if (gc > 63) gc = 63;
            xr[k] = x[((b * 3 + c) * 64 + (2 * r + rr)) * 64 + gc];
        }
    }
#pragma unroll
    for (int k = 0; k < 8; k++) {
        int i4 = k * 512 + t;
        if (i4 < 3600) {
            float v4[4] = { wr[k].x, wr[k].y, wr[k].z, wr[k].w };
#pragma unroll
            for (int e = 0; e < 4; e++) {
                int i = i4 * 4 + e, o = i / 225, jj = i % 225;
                wlds[o * 244 + (jj / 15) * 16 + (jj % 15)] = v4[e];
            }
        }
    }
#pragma unroll
    for (int k = 0; k < 2; k++) { int i = t + k * 512; if (i < 648) xsm[i] = xr[k]; }
    __syncthreads();

    int w = t >> 6, o = t & 63;
    int rw = w & 1, cq = w >> 1, base = cq * 8;

    float z1[8], z2[8], z3[8], s[8], q[8];
#pragma unroll
    for (int i = 0; i < 8; i++) { z1[i]=0; z2[i]=0; z3[i]=0; s[i]=0; q[i]=0; }
    float c01=0,c02=0,c03=0,c11=0,c12=0,c13=0,c22=0,c23=0,c33=0;  // Gram (folded)

    for (int c = 0; c < 3; c++) {
#pragma unroll
        for (int kh = 0; kh < 5; kh++) {
            float xv[12];
#pragma unroll
            for (int k = 0; k < 12; k++) xv[k] = xsm[(c * 6 + rw + kh) * 36 + base + k];
            float wf[16];
            const float* wp = &wlds[o * 244 + (c * 5 + kh) * 16];
            *(float4*)&wf[0]  = *(const float4*)&wp[0];
            *(float4*)&wf[4]  = *(const float4*)&wp[4];
            *(float4*)&wf[8]  = *(const float4*)&wp[8];
            *(float4*)&wf[12] = *(const float4*)&wp[12];
#pragma unroll
            for (int kw = 0; kw < 5; kw++) {
                float w1 = wf[kw * 3], w2v = wf[kw * 3 + 1], w3v = wf[kw * 3 + 2];
                c01 += w1; c02 += w2v; c03 += w3v;
                c11 += w1 * w1; c12 += w1 * w2v; c13 += w1 * w3v;
                c22 += w2v * w2v; c23 += w2v * w3v; c33 += w3v * w3v;
#pragma unroll
                for (int i = 0; i < 8; i++) {
                    float v = xv[kw + i];
                    s[i] += v; q[i] += v * v;
                    z1[i] += w1 * v; z2[i] += w2v * v; z3[i] += w3v * v;
                }
            }
        }
    }

    // 4x4 Gauss-Jordan inverse of the Gram matrix
    float gm[16];
    {
        float A[4][8];
        A[0][0]=75.f; A[0][1]=c01; A[0][2]=c02; A[0][3]=c03;
        A[1][0]=c01;  A[1][1]=c11; A[1][2]=c12; A[1][3]=c13;
        A[2][0]=c02;  A[2][1]=c12; A[2][2]=c22; A[2][3]=c23;
        A[3][0]=c03;  A[3][1]=c13; A[3][2]=c23; A[3][3]=c33;
#pragma unroll
        for (int i = 0; i < 4; i++)
#pragma unroll
            for (int j = 0; j < 4; j++) A[i][4 + j] = (i == j) ? 1.f : 0.f;
#pragma unroll
        for (int p = 0; p < 4; p++) {
            float ip = 1.f / A[p][p];
#pragma unroll
            for (int j = 0; j < 8; j++) A[p][j] *= ip;
#pragma unroll
            for (int i = 0; i < 4; i++) if (i != p) {
                float f = A[i][p];
#pragma unroll
                for (int j = 0; j < 8; j++) A[i][j] -= f * A[p][j];
            }
        }
#pragma unroll
        for (int i = 0; i < 4; i++)
#pragma unroll
            for (int j = 0; j < 4; j++) gm[i * 4 + j] = A[i][4 + j];
    }

    __syncthreads();   // wlds dead beyond here; part/redS/redQ alias it

    const float C1 = 0.36787944117144233f;
    const float INV = 1.5819767068693265f;
#pragma unroll
    for (int pp = 0; pp < 4; pp++) {
        int pl = cq * 4 + pp;
        if (pl < 15) {
            float aa = 0.f;
#pragma unroll
            for (int e = 0; e < 2; e++) {
                int i = 2 * pp + e;
                float sum = s[i], sq = q[i];
                float gg2 = (sq - sum * sum * (1.f / 75.f)) * (1.f / 74.f);
                float zf[4] = { sum, z1[i], z2[i], z3[i] };
                float qf = 0.f;
#pragma unroll
                for (int f = 0; f < 4; f++) {
                    float acc = 0.f;
#pragma unroll
                    for (int h = 0; h < 4; h++) acc += gm[f * 4 + h] * zf[h];
                    qf += acc * zf[f];
                }
                float err = (sq - qf) / (75.f * gg2);
                aa += (expf(-err) - C1) * INV - 0.5f;
            }
            part[(rw * 15 + pl) * 66 + o] = 0.25f * aa;
        }
    }
    __syncthreads();

    int j2 = t >> 6;
    float ps = 0.f, pq = 0.f;
    for (int pl = j2; pl < 15; pl += 8) {
        float v = part[pl * 66 + o] + part[(15 + pl) * 66 + o];
        g_h1[((b * 30 + r) * 30 + ch * 15 + pl) * 64 + o] = v;
        ps += v; pq += v * v;
    }
    redS[t] = ps; redQ[t] = pq;
    __syncthreads();
    if (t < 64) {
        float aS = 0.f, aQ = 0.f;
#pragma unroll
        for (int k = 0; k < 8; k++) { aS += redS[t + 64 * k]; aQ += redQ[t + 64 * k]; }
        atomicAdd(&stats[t],      aS);
        atomicAdd(&stats[64 + t], aQ);
    }
}

// -------- bn1 + conv2 + bn2 stats (+ w3 AND w4 repacks) --------
// grid 896 = (b4, oh28, owh2, ocg4); block 256 = oc_l(32) x grp(8);
// grp<6: 2 ow, grp>=6: 1 ow. 2 staging rounds x 2 tiles.
__global__ __launch_bounds__(256) void k_conv2(const float* __restrict__ w3,
                                               const float* __restrict__ w4,
                                               const float* __restrict__ g1,
                                               const float* __restrict__ b1,
                                               float* __restrict__ stats) {
    __shared__ __align__(16) float ws[2 * 32 * 148];
    __shared__ __align__(16) float xs[3 * 16 * 64];
    __shared__ float redS[256], redQ[256];
    int blk = blockIdx.x, t = threadIdx.x;
    int b = blk / 224, rem = blk % 224, oh = rem >> 3, sub = rem & 7;
    int owh = sub >> 2, ocg = sub & 3;
    int oc_l = t & 31, grp = t >> 5;
    int now = (grp < 6) ? 2 : 1;
    int lowb = (grp < 6) ? grp * 2 : 12 + (grp - 6);

    // w3 repack for k_conv3 (single guarded pass)
    {
        int j = blk * 256 + t;
        if (j < 147456) {
            int c = j & 3, s4 = j >> 2;
            int sl = s4 % 36, tmp = s4 / 36, oc2 = tmp & 31, bk = tmp >> 5;
            int it = bk & 7, og = bk >> 3;
            int kw = sl % 3, icq = (sl / 3) & 3, kh = sl / 12;
            int ic = it * 16 + icq * 4 + c;
            g_w3p[j] = w3[((og * 32 + oc2) * 128 + ic) * 9 + kh * 3 + kw];
        }
    }
    // w4 repack for k_conv4 (single guarded pass)
    {
        int j = blk * 256 + t;
        if (j < 147456) {
            int c = j & 3, s4 = j >> 2;
            int sl = s4 % 72, tmp = s4 / 72, oc2 = tmp & 15, blkq = tmp >> 4;
            int icq = blkq & 3, og = blkq >> 2;
            int kw = sl % 3, icb2 = (sl / 3) & 7, kh = sl / 24;
            int ic = icq * 32 + icb2 * 4 + c;
            g_w4p[j] = w4[((og * 16 + oc2) * 128 + ic) * 9 + kh * 3 + kw];
        }
    }

    const float4* wsrc = (const float4*)g_w2p + (ocg * 4) * 1152;
    {
        int icb = (t & 15) * 4;
        float4 S = *(const float4*)&stats[icb], Q = *(const float4*)&stats[64 + icb];
        float4 G4 = *(const float4*)&g1[icb], B4 = *(const float4*)&b1[icb];
        float scv[4], shv[4];
        float mm[4] = { S.x, S.y, S.z, S.w }, qq[4] = { Q.x, Q.y, Q.z, Q.w };
        float gg[4] = { G4.x, G4.y, G4.z, G4.w }, bb[4] = { B4.x, B4.y, B4.z, B4.w };
#pragma unroll
        for (int c = 0; c < 4; c++) {
            float m = mm[c] * (1.f / 3600.f);
            float v = qq[c] * (1.f / 3600.f) - m * m;
            scv[c] = gg[c] * rsqrtf(v + 1e-5f);
            shv[c] = bb[c] - m * scv[c];
        }
        int px = t >> 4, ic4 = t & 15;
        float4 xr[3];
#pragma unroll
        for (int k = 0; k < 3; k++)
            xr[k] = ((const float4*)g_h1)[((b * 30 + oh + k) * 30 + owh * 14 + px) * 16 + ic4];
        float4 wreg[9];
#pragma unroll
        for (int k = 0; k < 9; k++) wreg[k] = wsrc[k * 256 + t];
#pragma unroll
        for (int k = 0; k < 3; k++) {
            float4 v;
            v.x = xr[k].x * scv[0] + shv[0]; v.y = xr[k].y * scv[1] + shv[1];
            v.z = xr[k].z * scv[2] + shv[2]; v.w = xr[k].w * scv[3] + shv[3];
            *(float4*)&xs[((k * 16 + px) * 16 + ic4) * 4] = v;
        }
#pragma unroll
        for (int k = 0; k < 9; k++) {
            int idx = k * 256 + t;
            int tile = idx / 1152, r2 = idx % 1152;
            *(float4*)&ws[tile * 4736 + (r2 / 36) * 148 + (r2 % 36) * 4] = wreg[k];
        }
    }
    __syncthreads();

    float acc[2] = {0, 0};
    for (int rr = 0; rr < 2; ++rr) {
        float4 wreg[9];
        if (rr == 0) {
#pragma unroll
            for (int k = 0; k < 9; k++) wreg[k] = wsrc[2 * 1152 + k * 256 + t];
        }
        for (int half = 0; half < 2; ++half) {
            int it = rr * 2 + half;
            const float* wB = &ws[half * 4736 + oc_l * 148];
#pragma unroll 1
            for (int icq = 0; icq < 4; icq++) {
                int xoff = it * 16 + icq * 4;
#pragma unroll
                for (int kh = 0; kh < 3; kh++) {
                    const float* wb = &wB[(kh * 4 + icq) * 12];
                    float4 w0 = *(const float4*)&wb[0];
                    float4 w1 = *(const float4*)&wb[4];
                    float4 w2v = *(const float4*)&wb[8];
                    const float* xrow = &xs[(kh * 16 + lowb) * 64 + xoff];
                    float4 x0 = *(const float4*)&xrow[0];
                    float4 x1 = *(const float4*)&xrow[64];
#pragma unroll
                    for (int i = 0; i < 2; i++) {
                        if (i < now) {
                            float4 x2 = *(const float4*)&xrow[(i + 2) * 64];
                            acc[i] += w0.x * x0.x + w0.y * x0.y + w0.z * x0.z + w0.w * x0.w
                                    + w1.x * x1.x + w1.y * x1.y + w1.z * x1.z + w1.w * x1.w
                                    + w2v.x * x2.x + w2v.y * x2.y + w2v.z * x2.z + w2v.w * x2.w;
                            x0 = x1; x1 = x2;
                        }
                    }
                }
            }
        }
        if (rr == 0) {
            __syncthreads();
#pragma unroll
            for (int k = 0; k < 9; k++) {
                int idx = k * 256 + t;
                int tile = idx / 1152, r2 = idx % 1152;
                *(float4*)&ws[tile * 4736 + (r2 / 36) * 148 + (r2 % 36) * 4] = wreg[k];
            }
            __syncthreads();
        }
    }
    int oc = ocg * 32 + oc_l;
    float ps = 0.f, pq = 0.f;
#pragma unroll
    for (int i = 0; i < 2; i++) {
        if (i < now) {
            int ow = owh * 14 + lowb + i;
            g_h2[(((b * 14 + (oh >> 1)) * 14 + (ow >> 1)) * 4 + (oh & 1) * 2 + (ow & 1)) * 128 + oc] = acc[i];
            ps += acc[i]; pq += acc[i] * acc[i];
        }
    }
    redS[t] = ps; redQ[t] = pq;
    __syncthreads();
    if (t < 32) {
        float aS = 0.f, aQ = 0.f;
#pragma unroll
        for (int k = 0; k < 8; k++) { aS += redS[t + 32 * k]; aQ += redQ[t + 32 * k]; }
        atomicAdd(&stats[128 + ocg * 32 + t], aS);
        atomicAdd(&stats[256 + ocg * 32 + t], aQ);
    }
}

// -------- bn2+relu+avgpool2 + conv3 + bn3 stats (preamble-free) --------
// grid 192 = (b4, oh12, ocg4); block 256 = oc_l(32) x grp(8);
// grp<4: 2 ow, grp>=4: 1 ow. 4 staging rounds x 2 tiles.
__global__ __launch_bounds__(256) void k_conv3(const float* __restrict__ g2,
                                               const float* __restrict__ b2,
                                               float* __restrict__ stats) {
    __shared__ __align__(16) float ws[2 * 32 * 148];
    __shared__ __align__(16) float xs[3 * 14 * 128];
    __shared__ float redS[256], redQ[256];
    int blk = blockIdx.x, t = threadIdx.x;
    int b = blk / 48, rem = blk % 48, oh = rem >> 2, ocg = rem & 3;
    int oc_l = t & 31, grp = t >> 5;
    int now = (grp < 4) ? 2 : 1;
    int lowb = (grp < 4) ? grp * 2 : 8 + (grp - 4);

    const float4* wsrc = (const float4*)g_w3p + (ocg * 8) * 1152;
    {
        int icb = (t & 31) * 4;
        float4 S = *(const float4*)&stats[128 + icb], Q = *(const float4*)&stats[256 + icb];
        float4 G4 = *(const float4*)&g2[icb], B4 = *(const float4*)&b2[icb];
        float scv[4], shv[4];
        float mm[4] = { S.x, S.y, S.z, S.w }, qq[4] = { Q.x, Q.y, Q.z, Q.w };
        float gg[4] = { G4.x, G4.y, G4.z, G4.w }, bb[4] = { B4.x, B4.y, B4.z, B4.w };
#pragma unroll
        for (int c = 0; c < 4; c++) {
            float m = mm[c] * (1.f / 3136.f);
            float v = qq[c] * (1.f / 3136.f) - m * m;
            scv[c] = gg[c] * rsqrtf(v + 1e-5f);
            shv[c] = bb[c] - m * scv[c];
        }
        float4 wreg[9];
#pragma unroll
        for (int k = 0; k < 9; k++) wreg[k] = wsrc[k * 256 + t];
        float4 pa[6], pb[6], pc[6], pd[6];
#pragma unroll
        for (int k = 0; k < 6; k++) {
            int i4 = t + k * 256;
            if (i4 < 1344) {
                int px = (i4 >> 5) % 14, rr2 = i4 / 448;
                const float4* p0 = (const float4*)&g_h2[(((b * 14 + oh + rr2) * 14 + px) * 4) * 128 + (i4 & 31) * 4];
                pa[k] = p0[0]; pb[k] = p0[32]; pc[k] = p0[64]; pd[k] = p0[96];
            }
        }
#pragma unroll
        for (int k = 0; k < 9; k++) {
            int idx = k * 256 + t;
            int tile = idx / 1152, r2 = idx % 1152;
            *(float4*)&ws[tile * 4736 + (r2 / 36) * 148 + (r2 % 36) * 4] = wreg[k];
        }
#pragma unroll
        for (int k = 0; k < 6; k++) {
            int i4 = t + k * 256;
            if (i4 < 1344) {
                float4 o4;
                o4.x = 0.25f * (fmaxf(pa[k].x * scv[0] + shv[0], 0.f) + fmaxf(pb[k].x * scv[0] + shv[0], 0.f)
                              + fmaxf(pc[k].x * scv[0] + shv[0], 0.f) + fmaxf(pd[k].x * scv[0] + shv[0], 0.f));
                o4.y = 0.25f * (fmaxf(pa[k].y * scv[1] + shv[1], 0.f) + fmaxf(pb[k].y * scv[1] + shv[1], 0.f)
                              + fmaxf(pc[k].y * scv[1] + shv[1], 0.f) + fmaxf(pd[k].y * scv[1] + shv[1], 0.f));
                o4.z = 0.25f * (fmaxf(pa[k].z * scv[2] + shv[2], 0.f) + fmaxf(pb[k].z * scv[2] + shv[2], 0.f)
                              + fmaxf(pc[k].z * scv[2] + shv[2], 0.f) + fmaxf(pd[k].z * scv[2] + shv[2], 0.f));
                o4.w = 0.25f * (fmaxf(pa[k].w * scv[3] + shv[3], 0.f) + fmaxf(pb[k].w * scv[3] + shv[3], 0.f)
                              + fmaxf(pc[k].w * scv[3] + shv[3], 0.f) + fmaxf(pd[k].w * scv[3] + shv[3], 0.f));
                *(float4*)&xs[i4 * 4] = o4;
            }
        }
    }
    __syncthreads();

    float acc[2] = {0, 0};
    for (int rr = 0; rr < 4; ++rr) {
        float4 wreg[9];
        if (rr < 3) {
#pragma unroll
            for (int k = 0; k < 9; k++) wreg[k] = wsrc[(2 * rr + 2) * 1152 + k * 256 + t];
        }
        for (int half = 0; half < 2; ++half) {
            int it = rr * 2 + half;
            const float* wB = &ws[half * 4736 + oc_l * 148];
#pragma unroll 1
            for (int icq = 0; icq < 4; icq++) {
                int xoff = it * 16 + icq * 4;
#pragma unroll
                for (int kh = 0; kh < 3; kh++) {
                    const float* wb = &wB[(kh * 4 + icq) * 12];
                    float4 w0 = *(const float4*)&wb[0];
                    float4 w1 = *(const float4*)&wb[4];
                    float4 w2v = *(const float4*)&wb[8];
                    const float* xrow = &xs[(kh * 14 + lowb) * 128 + xoff];
                    float4 x0 = *(const float4*)&xrow[0];
                    float4 x1 = *(const float4*)&xrow[128];
#pragma unroll
                    for (int i = 0; i < 2; i++) {
                        if (i < now) {
                            float4 x2 = *(const float4*)&xrow[(i + 2) * 128];
                            acc[i] += w0.x * x0.x + w0.y * x0.y + w0.z * x0.z + w0.w * x0.w
                                    + w1.x * x1.x + w1.y * x1.y + w1.z * x1.z + w1.w * x1.w
                                    + w2v.x * x2.x + w2v.y * x2.y + w2v.z * x2.z + w2v.w * x2.w;
                            x0 = x1; x1 = x2;
                        }
                    }
                }
            }
        }
        if (rr < 3) {
            __syncthreads();
#pragma unroll
            for (int k = 0; k < 9; k++) {
                int idx = k * 256 + t;
                int tile = idx / 1152, r2 = idx % 1152;
                *(float4*)&ws[tile * 4736 + (r2 / 36) * 148 + (r2 % 36) * 4] = wreg[k];
            }
            __syncthreads();
        }
    }
    int oc = ocg * 32 + oc_l;
    float ps = 0.f, pq = 0.f;
#pragma unroll
    for (int i = 0; i < 2; i++) {
        if (i < now) {
            int ow = lowb + i;
            g_h3[(((b * 6 + (oh >> 1)) * 6 + (ow >> 1)) * 4 + (oh & 1) * 2 + (ow & 1)) * 128 + oc] = acc[i];
            ps += acc[i]; pq += acc[i] * acc[i];
        }
    }
    redS[t] = ps; redQ[t] = pq;
    __syncthreads();
    if (t < 32) {
        float aS = 0.f, aQ = 0.f;
#pragma unroll
        for (int k = 0; k < 8; k++) { aS += redS[t + 32 * k]; aQ += redQ[t + 32 * k]; }
        atomicAdd(&stats[384 + ocg * 32 + t], aS);
        atomicAdd(&stats[512 + ocg * 32 + t], aQ);
    }
}

// -------- bn3+relu+maxpool2 + conv4 + bn4 stats --------
// grid 128 = (b, oh4, ocg8); block 256 = oc_l(16) x ow(4) x icq(4=wave)
__global__ __launch_bounds__(256) void k_conv4(const float* __restrict__ g3,
                                               const float* __restrict__ b3,
                                               float* __restrict__ stats) {
    __shared__ __align__(16) float ws[64 * 292];
    __shared__ __align__(16) float xs[3 * 6 * 128];
    __shared__ float red[256];
    int blk = blockIdx.x, t = threadIdx.x;
    int b = blk / 32, rem = blk % 32, oh = rem / 8, ocg = rem % 8;
    int oc_l = t & 15, ow = (t >> 4) & 3, icq = t >> 6;

    {
        int icb = (t & 31) * 4;
        float4 S = *(const float4*)&stats[384 + icb], Q = *(const float4*)&stats[512 + icb];
        float4 G4 = *(const float4*)&g3[icb], B4 = *(const float4*)&b3[icb];
        float scv[4], shv[4];
        float mm[4] = { S.x, S.y, S.z, S.w }, qq[4] = { Q.x, Q.y, Q.z, Q.w };
        float gg[4] = { G4.x, G4.y, G4.z, G4.w }, bb[4] = { B4.x, B4.y, B4.z, B4.w };
#pragma unroll
        for (int c = 0; c < 4; c++) {
            float m = mm[c] * (1.f / 576.f);
            float v = qq[c] * (1.f / 576.f) - m * m;
            scv[c] = gg[c] * rsqrtf(v + 1e-5f);
            shv[c] = bb[c] - m * scv[c];
        }
        const float4* wsrc = (const float4*)g_w4p + ocg * 4608;
        float4 wreg[18];
#pragma unroll
        for (int k = 0; k < 18; k++) wreg[k] = wsrc[k * 256 + t];
        float4 pa[3], pb[3], pc[3], pd[3];
#pragma unroll
        for (int k = 0; k < 3; k++) {
            int i4 = t + k * 256;
            if (i4 < 576) {
                int px = (i4 >> 5) % 6, rr = i4 / 192;
                const float4* p0 = (const float4*)&g_h3[(((b * 6 + oh + rr) * 6 + px) * 4) * 128 + (i4 & 31) * 4];
                pa[k] = p0[0]; pb[k] = p0[32]; pc[k] = p0[64]; pd[k] = p0[96];
            }
        }
#pragma unroll
        for (int k = 0; k < 18; k++) {
            int idx = k * 256 + t;
            *(float4*)&ws[(idx / 72) * 292 + (idx % 72) * 4] = wreg[k];
        }
#pragma unroll
        for (int k = 0; k < 3; k++) {
            int i4 = t + k * 256;
            if (i4 < 576) {
                float4 o4;
                o4.x = fmaxf(fmaxf(fmaxf(pa[k].x * scv[0] + shv[0], pb[k].x * scv[0] + shv[0]),
                                   fmaxf(pc[k].x * scv[0] + shv[0], pd[k].x * scv[0] + shv[0])), 0.f);
                o4.y = fmaxf(fmaxf(fmaxf(pa[k].y * scv[1] + shv[1], pb[k].y * scv[1] + shv[1]),
                                   fmaxf(pc[k].y * scv[1] + shv[1], pd[k].y * scv[1] + shv[1])), 0.f);
                o4.z = fmaxf(fmaxf(fmaxf(pa[k].z * scv[2] + shv[2], pb[k].z * scv[2] + shv[2]),
                                   fmaxf(pc[k].z * scv[2] + shv[2], pd[k].z * scv[2] + shv[2])), 0.f);
                o4.w = fmaxf(fmaxf(fmaxf(pa[k].w * scv[3] + shv[3], pb[k].w * scv[3] + shv[3]),
                                   fmaxf(pc[k].w * scv[3] + shv[3], pd[k].w * scv[3] + shv[3])), 0.f);
                *(float4*)&xs[i4 * 4] = o4;
            }
        }
    }
    __syncthreads();

    float acc = 0.f;
    const float* wbase = &ws[(icq * 16 + oc_l) * 292];
#pragma unroll 1
    for (int icbq = 0; icbq < 8; icbq++) {
#pragma unroll
        for (int kh = 0; kh < 3; kh++) {
            const float* wb = &wbase[(kh * 8 + icbq) * 12];
            float4 w0 = *(const float4*)&wb[0];
            float4 w1 = *(const float4*)&wb[4];
            float4 w2v = *(const float4*)&wb[8];
            float4 x0 = *(const float4*)&xs[(kh * 6 + ow) * 128 + icq * 32 + icbq * 4];
            float4 x1 = *(const float4*)&xs[(kh * 6 + ow + 1) * 128 + icq * 32 + icbq * 4];
            float4 x2 = *(const float4*)&xs[(kh * 6 + ow + 2) * 128 + icq * 32 + icbq * 4];
            acc += w0.x * x0.x + w0.y * x0.y + w0.z * x0.z + w0.w * x0.w
                 + w1.x * x1.x + w1.y * x1.y + w1.z * x1.z + w1.w * x1.w
                 + w2v.x * x2.x + w2v.y * x2.y + w2v.z * x2.z + w2v.w * x2.w;
        }
    }
    red[t] = acc;
    __syncthreads();
    if (t < 64) {
        float v = red[t] + red[t + 64] + red[t + 128] + red[t + 192];
        int oc = ocg * 16 + (t & 15);
        g_h4[((b * 4 + oh) * 4 + (t >> 4)) * 128 + oc] = v;
        float ps = v + __shfl_xor(v, 16);  ps += __shfl_xor(ps, 32);
        float pv = v * v;
        float pq = pv + __shfl_xor(pv, 16); pq += __shfl_xor(pq, 32);
        if (t < 16) {
            atomicAdd(&stats[640 + ocg * 16 + t], ps);
            atomicAdd(&stats[768 + ocg * 16 + t], pq);
        }
    }
}

// ------- bn4+relu+maxpool4 + FC -------
__global__ __launch_bounds__(256) void k_final(const float* __restrict__ g4,
                                               const float* __restrict__ b4,
                                               const float* __restrict__ fcw,
                                               const float* __restrict__ fcb,
                                               const float* __restrict__ stats,
                                               float* __restrict__ out) {
    __shared__ float sc[128], sh[128];
    __shared__ float pooled[4][128];
    int t = threadIdx.x;
    if (t < 128) {
        float m = stats[640 + t] * (1.f / 64.f);
        float v = stats[768 + t] * (1.f / 64.f) - m * m;
        float rs = rsqrtf(v + 1e-5f);
        sc[t] = g4[t] * rs; sh[t] = b4[t] - m * sc[t];
    }
    __syncthreads();
    for (int item = t; item < 512; item += 256) {
        int bb = item >> 7, oc = item & 127;
        float s = sc[oc], h = sh[oc];
        float mx = 0.f;
#pragma unroll
        for (int k = 0; k < 16; k++) mx = fmaxf(mx, g_h4[(bb * 16 + k) * 128 + oc] * s + h);
        pooled[bb][oc] = mx;
    }
    __syncthreads();
    if (t < 20) {
        int bb = t / 5, cls = t % 5;
        float acc = fcb[cls];
        const float* w = &fcw[cls * 128];
        for (int oc = 0; oc < 128; oc++) acc += pooled[bb][oc] * w[oc];
        out[bb * 5 + cls] = acc;
    }
}

extern "C" void kernel_launch(void* const* d_in, const int* in_sizes, int n_in,
                              void* d_out, int out_size, void* d_ws, size_t ws_size,
                              hipStream_t stream) {
    (void)in_sizes; (void)n_in; (void)out_size; (void)ws_size;
    const float* x     = (const float*)d_in[0];
    const float* srn_w = (const float*)d_in[1];
    const float* w2    = (const float*)d_in[2];
    const float* w3    = (const float*)d_in[4];
    const float* w4    = (const float*)d_in[6];
    const float* g1 = (const float*)d_in[8];  const float* b1 = (const float*)d_in[9];
    const float* g2 = (const float*)d_in[10]; const float* b2 = (const float*)d_in[11];
    const float* g3 = (const float*)d_in[12]; const float* b3 = (const float*)d_in[13];
    const float* g4 = (const float*)d_in[14]; const float* b4 = (const float*)d_in[15];
    const float* fcw = (const float*)d_in[16]; const float* fcb = (const float*)d_in[17];
    float* out = (float*)d_out;
    float* stats = (float*)d_ws;   // 896 floats of BN-stat accumulators

    hipMemsetAsync(d_ws, 0, 4096, stream);
    k_srn  <<<dim3(240), dim3(512), 0, stream>>>(x, srn_w, w2, stats);
    k_conv2<<<dim3(896), dim3(256), 0, stream>>>(w3, w4, g1, b1, stats);
    k_conv3<<<dim3(192), dim3(256), 0, stream>>>(g2, b2, stats);
    k_conv4<<<dim3(128), dim3(256), 0, stream>>>(g3, b3, stats);
    k_final<<<dim3(1),   dim3(256), 0, stream>>>(g4, b4, fcw, fcb, stats, out);
}